// Round 1
// baseline (146.629 us; speedup 1.0000x reference)
//
#include <hip/hip_runtime.h>
#include <math.h>

// Soft-argmax centroid over [B,K,128,128] fp32 heatmaps, two inputs.
// One 256-thread block per (input, b*k) unit: 16384 floats = 4096 float4.
// Memory-bound: 128 MiB total read.

#define HM_H 128
#define HM_W 128

__global__ __launch_bounds__(256) void centroid_kernel(
    const float* __restrict__ hm0,
    const float* __restrict__ hm1,
    float* __restrict__ out,
    int BK)  // number of (b,k) units per input
{
    const int unit  = blockIdx.x;            // 0 .. 2*BK-1
    const int which = (unit >= BK) ? 1 : 0;  // 0 -> hm0, 1 -> hm1
    const int bk    = which ? (unit - BK) : unit;

    const float* __restrict__ src =
        (which ? hm1 : hm0) + (size_t)bk * (HM_H * HM_W);
    float* __restrict__ dst = out + (size_t)which * (size_t)BK * 2 + (size_t)bk * 2;

    const int t = threadIdx.x;

    float s = 0.0f;   // sum v
    float sx = 0.0f;  // sum w*v
    float sy = 0.0f;  // sum h*v

    const float4* __restrict__ p = (const float4*)src;
    // 4096 float4 per unit / 256 threads = 16 per thread, stride 256 (coalesced)
#pragma unroll
    for (int it = 0; it < 16; ++it) {
        const int f4 = t + it * 256;     // float4 index within unit
        const float4 v = p[f4];
        const int fe = f4 << 2;          // element index
        const float h = (float)(fe >> 7);
        const float w = (float)(fe & 127);
        const float sv = v.x + v.y + v.z + v.w;
        s  += sv;
        sy += h * sv;
        sx += w * sv + (v.y + 2.0f * v.z + 3.0f * v.w);
    }

    // wave-level reduce (wave = 64 lanes)
#pragma unroll
    for (int off = 32; off > 0; off >>= 1) {
        s  += __shfl_down(s,  off, 64);
        sx += __shfl_down(sx, off, 64);
        sy += __shfl_down(sy, off, 64);
    }

    __shared__ float ls[4], lx[4], ly[4];
    const int wid  = t >> 6;
    const int lane = t & 63;
    if (lane == 0) { ls[wid] = s; lx[wid] = sx; ly[wid] = sy; }
    __syncthreads();

    if (t == 0) {
        const float S = ls[0] + ls[1] + ls[2] + ls[3];
        const float X = lx[0] + lx[1] + lx[2] + lx[3];
        const float Y = ly[0] + ly[1] + ly[2] + ly[3];
        // jnp.round == round-half-to-even == rintf (default FE_TONEAREST)
        dst[0] = rintf(X / S);
        dst[1] = rintf(Y / S);
    }
}

extern "C" void kernel_launch(void* const* d_in, const int* in_sizes, int n_in,
                              void* d_out, int out_size, void* d_ws, size_t ws_size,
                              hipStream_t stream) {
    const float* hm0 = (const float*)d_in[0];
    const float* hm1 = (const float*)d_in[1];
    float* out = (float*)d_out;

    const int BK = out_size / 4;  // B*K (out = 2 tensors * BK * 2 coords)
    const int grid = 2 * BK;      // one block per (input, bk) unit

    centroid_kernel<<<grid, 256, 0, stream>>>(hm0, hm1, out, BK);
}

// Round 3
// 144.774 us; speedup vs baseline: 1.0128x; 1.0128x over previous
//
#include <hip/hip_runtime.h>
#include <math.h>

// Soft-argmax centroid over [B,K,128,128] fp32 heatmaps, two inputs.
// Stage 1: 4 blocks per (input,b,k) unit, 256 threads each; every thread
//          loads 4 independent float4 (batched, no register reuse chain),
//          reduces {sum, sum*x, sum*y} per block -> partials in d_ws.
// Stage 2: one thread per unit sums the 4 partials, divides, rounds.

#define HM_H 128
#define HM_W 128
#define PARTS 4            // blocks per unit; each covers 32 rows (16 KB)

__global__ __launch_bounds__(256) void centroid_partial(
    const float* __restrict__ hm0,
    const float* __restrict__ hm1,
    float* __restrict__ ws,
    int BK)
{
    const int gb   = blockIdx.x;          // 0 .. 2*BK*PARTS-1
    const int part = gb & (PARTS - 1);
    const int u    = gb >> 2;             // unit: 0 .. 2*BK-1
    const int bk   = (u >= BK) ? (u - BK) : u;
    const float* __restrict__ src =
        ((u >= BK) ? hm1 : hm0) + (size_t)bk * (HM_H * HM_W);

    const float4* __restrict__ p = (const float4*)src + part * 1024;
    const int t = threadIdx.x;

    // ---- batched independent loads (4 float4 in flight per thread) ----
    const float4 v0 = p[t];
    const float4 v1 = p[t + 256];
    const float4 v2 = p[t + 512];
    const float4 v3 = p[t + 768];

    // column of this thread's 4-elem group (same for all 4 loads)
    const float wbase = (float)((t << 2) & (HM_W - 1));
    // local row of load k: rl = (t>>5) + 8*k  (each 256-float4 chunk = 8 rows)
    const float rl = (float)(t >> 5);

    const float sv0 = v0.x + v0.y + v0.z + v0.w;
    const float sv1 = v1.x + v1.y + v1.z + v1.w;
    const float sv2 = v2.x + v2.y + v2.z + v2.w;
    const float sv3 = v3.x + v3.y + v3.z + v3.w;

    float s  = sv0 + sv1 + sv2 + sv3;
    float sx = wbase * s
             + (v0.y + v1.y + v2.y + v3.y)
             + 2.0f * (v0.z + v1.z + v2.z + v3.z)
             + 3.0f * (v0.w + v1.w + v2.w + v3.w);
    // global row = part*32 + rl + 8k  ->  sy = part*32*s + sum((rl+8k)*sv)
    float sy = rl * (sv0 + sv1 + sv2 + sv3)
             + 8.0f * (sv1 + 2.0f * sv2 + 3.0f * sv3)
             + (float)(part * 32) * s;

    // ---- wave (64-lane) butterfly reduce ----
#pragma unroll
    for (int off = 32; off > 0; off >>= 1) {
        s  += __shfl_down(s,  off, 64);
        sx += __shfl_down(sx, off, 64);
        sy += __shfl_down(sy, off, 64);
    }

    __shared__ float ls[4], lx[4], ly[4];
    const int wid  = t >> 6;
    const int lane = t & 63;
    if (lane == 0) { ls[wid] = s; lx[wid] = sx; ly[wid] = sy; }
    __syncthreads();

    if (t == 0) {
        ws[gb * 3 + 0] = ls[0] + ls[1] + ls[2] + ls[3];
        ws[gb * 3 + 1] = lx[0] + lx[1] + lx[2] + lx[3];
        ws[gb * 3 + 2] = ly[0] + ly[1] + ly[2] + ly[3];
    }
}

__global__ __launch_bounds__(256) void centroid_final(
    const float* __restrict__ ws,
    float* __restrict__ out,
    int nunits)
{
    const int u = blockIdx.x * 256 + threadIdx.x;
    if (u >= nunits) return;
    const float* __restrict__ w = ws + (size_t)u * (PARTS * 3);
    float S = 0.0f, X = 0.0f, Y = 0.0f;
#pragma unroll
    for (int pr = 0; pr < PARTS; ++pr) {
        S += w[pr * 3 + 0];
        X += w[pr * 3 + 1];
        Y += w[pr * 3 + 2];
    }
    // out = [keypoint (BK*2), tf_keypoint (BK*2)]; u spans both halves in order
    out[u * 2 + 0] = rintf(X / S);   // round-half-to-even == jnp.round
    out[u * 2 + 1] = rintf(Y / S);
}

extern "C" void kernel_launch(void* const* d_in, const int* in_sizes, int n_in,
                              void* d_out, int out_size, void* d_ws, size_t ws_size,
                              hipStream_t stream) {
    const float* hm0 = (const float*)d_in[0];
    const float* hm1 = (const float*)d_in[1];
    float* out = (float*)d_out;
    float* ws  = (float*)d_ws;

    const int BK     = out_size / 4;   // B*K
    const int nunits = 2 * BK;
    const int grid1  = nunits * PARTS;

    centroid_partial<<<grid1, 256, 0, stream>>>(hm0, hm1, ws, BK);
    centroid_final<<<(nunits + 255) / 256, 256, 0, stream>>>(ws, out, nunits);
}